// Round 13
// baseline (394.387 us; speedup 1.0000x reference)
//
#include <hip/hip_runtime.h>

// Problem constants (fixed by reference)
#define B_ROWS 8192
#define E_DIM  256
#define H_DIM  4096

typedef __attribute__((ext_vector_type(8))) short short8;
typedef __attribute__((ext_vector_type(4))) float f32x4;

typedef __attribute__((address_space(1))) const void* gas1_t;
typedef __attribute__((address_space(3))) void*       las3_t;

__device__ __forceinline__ float b2f(unsigned short s) {
    return __uint_as_float(((unsigned)s) << 16);
}
__device__ __forceinline__ unsigned short f2b(float f) {
    unsigned u = __float_as_uint(f);
    u += 0x7fffu + ((u >> 16) & 1u);   // RNE
    return (unsigned short)(u >> 16);
}

// LDS swizzle for BK=32 (64B rows, 4x16B slots): slot' = slot ^ ((row>>1)&3)
// -> ds_read_b128 fragment reads are 2-way (free, m136) instead of 8-way.
__device__ __forceinline__ int swz(int row, int slot) {
    return slot ^ ((row >> 1) & 3);
}

// ---------------------------------------------------------------------------
// Transpose + cast f32 [R,C] -> bf16 [C,R]
__global__ void k_transpose_cast(const float* __restrict__ in,
                                 unsigned short* __restrict__ out,
                                 int R, int C) {
    __shared__ float tile[32][33];
    const int c0 = blockIdx.x * 32, r0 = blockIdx.y * 32;
    const int tx = threadIdx.x & 31, ty = threadIdx.x >> 5;  // ty 0..7
#pragma unroll
    for (int j = 0; j < 4; ++j)
        tile[ty * 4 + j][tx] = in[(size_t)(r0 + ty * 4 + j) * C + c0 + tx];
    __syncthreads();
#pragma unroll
    for (int j = 0; j < 4; ++j)
        out[(size_t)(c0 + ty * 4 + j) * R + r0 + tx] = f2b(tile[tx][ty * 4 + j]);
}

// ---------------------------------------------------------------------------
// Cast f32 -> bf16, 4 elems/thread.
__global__ void k_cast_bf16(const float* __restrict__ in,
                            unsigned short* __restrict__ out, int n4) {
    int i = blockIdx.x * blockDim.x + threadIdx.x;
    if (i < n4) {
        float4 v = ((const float4*)in)[i];
        ushort4 o;
        o.x = f2b(v.x); o.y = f2b(v.y); o.z = f2b(v.z); o.w = f2b(v.w);
        ((ushort4*)out)[i] = o;
    }
}

// ---------------------------------------------------------------------------
// GEMM1: h[M,N] = A[M,K] * Bt[N,K]^T, bf16 out + fused column sum/sumsq.
// BM=BN=128, BK=32, swizzled global_load_lds staging. grid (N/128, M/128).
__global__ __launch_bounds__(256) void k_gemm1(
    const unsigned short* __restrict__ A, const unsigned short* __restrict__ Bt,
    unsigned short* __restrict__ Cout,
    float* __restrict__ cs, float* __restrict__ cs2,
    int M, int N, int K) {
    constexpr int BK = 32, BM = 128, BN = 128;
    constexpr int MI = 4, NI = 4;
    __shared__ __align__(16) short As[BM * BK];
    __shared__ __align__(16) short Bs[BN * BK];

    const int t = threadIdx.x;
    const int lane = t & 63, wv = t >> 6;
    const int wr = wv >> 1, wc = wv & 1;
    const int l15 = lane & 15, quad = lane >> 4;
    const int m0 = blockIdx.y * BM, n0 = blockIdx.x * BN;

    f32x4 acc[MI][NI] = {};

    for (int k0 = 0; k0 < K; k0 += BK) {
#pragma unroll
        for (int q = 0; q < 2; ++q) {
            int u = q * 256 + t;
            int row = u >> 2, kc = swz(row, u & 3);
            const short* gp = (const short*)A + (size_t)(m0 + row) * K + k0 + kc * 8;
            short* lp = As + (size_t)(q * 256 + (wv << 6)) * 8;  // wave-uniform base
            __builtin_amdgcn_global_load_lds((gas1_t)gp, (las3_t)lp, 16, 0, 0);
        }
#pragma unroll
        for (int q = 0; q < 2; ++q) {
            int u = q * 256 + t;
            int row = u >> 2, kc = swz(row, u & 3);
            const short* gp = (const short*)Bt + (size_t)(n0 + row) * K + k0 + kc * 8;
            short* lp = Bs + (size_t)(q * 256 + (wv << 6)) * 8;
            __builtin_amdgcn_global_load_lds((gas1_t)gp, (las3_t)lp, 16, 0, 0);
        }
        __syncthreads();

        short8 af[MI], bfr[NI];
#pragma unroll
        for (int mi = 0; mi < MI; ++mi) {
            int row = wr * 64 + mi * 16 + l15;
            af[mi] = *(const short8*)(As + row * BK + (swz(row, quad) << 3));
        }
#pragma unroll
        for (int ni = 0; ni < NI; ++ni) {
            int row = wc * 64 + ni * 16 + l15;
            bfr[ni] = *(const short8*)(Bs + row * BK + (swz(row, quad) << 3));
        }
#pragma unroll
        for (int mi = 0; mi < MI; ++mi)
#pragma unroll
            for (int ni = 0; ni < NI; ++ni)
                acc[mi][ni] = __builtin_amdgcn_mfma_f32_16x16x32_bf16(
                    af[mi], bfr[ni], acc[mi][ni], 0, 0, 0);
        __syncthreads();
    }

    // epilogue: C/D layout col=lane&15, row=quad*4+reg (measured m89)
#pragma unroll
    for (int ni = 0; ni < NI; ++ni) {
        float s = 0.f, s2 = 0.f;
#pragma unroll
        for (int mi = 0; mi < MI; ++mi)
#pragma unroll
            for (int r = 0; r < 4; ++r) {
                int row = m0 + wr * 64 + mi * 16 + quad * 4 + r;
                int col = n0 + wc * 64 + ni * 16 + l15;
                float v = acc[mi][ni][r];
                Cout[(size_t)row * N + col] = f2b(v);
                s += v; s2 += v * v;
            }
        s  += __shfl_xor(s, 16);  s  += __shfl_xor(s, 32);
        s2 += __shfl_xor(s2, 16); s2 += __shfl_xor(s2, 32);
        if (quad == 0) {
            int col = n0 + wc * 64 + ni * 16 + l15;
            atomicAdd(&cs[col], s);
            atomicAdd(&cs2[col], s2);
        }
    }
}

// BN scale/shift packed as bf16 pair: ssb[k] = f2b(scale)<<16 | f2b(shift)
// (bf16 params verified numerically R6/R9/R10: absmax 7.6e-6 vs 2e-5 thr)
__global__ void k_bnprep(const float* __restrict__ sum, const float* __restrict__ sumsq,
                         const float* __restrict__ gamma, const float* __restrict__ beta,
                         unsigned* __restrict__ ssb) {
    int j = blockIdx.x * 256 + threadIdx.x;
    float mu = sum[j] * (1.f / B_ROWS);
    float var = sumsq[j] * (1.f / B_ROWS) - mu * mu;
    float sc = gamma[j] * rsqrtf(var + 1e-5f);
    float sh = beta[j] - mu * sc;
    ssb[j] = ((unsigned)f2b(sc) << 16) | (unsigned)f2b(sh);
}

__device__ __forceinline__ short8 bnrelu8(uint4 hv, uint4 sa, uint4 sb) {
    const unsigned short* hu = (const unsigned short*)&hv;
    const unsigned* wa = (const unsigned*)&sa;
    const unsigned* wb = (const unsigned*)&sb;
    short8 o;
#pragma unroll
    for (int j = 0; j < 8; ++j) {
        unsigned w = j < 4 ? wa[j] : wb[j - 4];
        float sc = __uint_as_float(w & 0xffff0000u);
        float sh = __uint_as_float(w << 16);
        float v = fmaxf(b2f(hu[j]) * sc + sh, 0.f);
        o[j] = (short)f2b(v);
    }
    return o;
}

// ---------------------------------------------------------------------------
// GEMM2, R13: m97 geometry (128x128, 16 MFMA/wave/iter) with R10's winning
// register-staged double-buffer (lgkm-only barrier):
// q[M,N] += relu(bn(h))[M,K] * W2T[N,K]^T.  BK=32, split-K x8 (1024 blocks).
// Per thread per iter: 2 A-chunks (bnrelu, SHARED BN params - same k-cols),
// 2 B-chunks; 4 ds_writes; ONE barrier; prefetch after barrier; 8 ds_reads;
// 16 MFMA. fp32 atomicAdd epilogue; bias added by z==0.
__global__ __launch_bounds__(256) void k_gemm2r(
    const unsigned short* __restrict__ A, const unsigned short* __restrict__ Bt,
    float* __restrict__ Cout, const float* __restrict__ bias,
    const unsigned* __restrict__ ssb,
    int M, int N, int K) {
    constexpr int BK = 32, BM = 128, BN = 128;
    __shared__ __align__(16) short As[2][BM * BK];   // 2 x 8 KB
    __shared__ __align__(16) short Bs[2][BN * BK];   // 2 x 8 KB

    const int t = threadIdx.x;
    const int lane = t & 63, wv = t >> 6;
    const int wr = wv >> 1, wc = wv & 1;
    const int l15 = lane & 15, quad = lane >> 4;
    const int m0 = blockIdx.y * BM, n0 = blockIdx.x * BN;

    const int Kc = K / gridDim.z;
    const int kbeg = blockIdx.z * Kc;
    const int ITERS = Kc / BK;

    const int r0 = t >> 2, akc = t & 3;
    const unsigned short* hp0 = A + (size_t)(m0 + r0) * K + akc * 8;
    const unsigned short* hp1 = A + (size_t)(m0 + 64 + r0) * K + akc * 8;
    const unsigned short* bp0 = Bt + (size_t)(n0 + r0) * K + akc * 8;
    const unsigned short* bp1 = Bt + (size_t)(n0 + 64 + r0) * K + akc * 8;
    const unsigned* ssp = ssb + akc * 8;
    const int w0 = r0 * BK + (swz(r0, akc) << 3);
    const int w1 = (64 + r0) * BK + (swz(64 + r0, akc) << 3);

    f32x4 acc[4][4] = {};

    uint4 h0 = *(const uint4*)(hp0 + kbeg);
    uint4 h1 = *(const uint4*)(hp1 + kbeg);
    uint4 sa = *(const uint4*)(ssp + kbeg);
    uint4 sb = *(const uint4*)(ssp + kbeg + 4);
    uint4 b0 = *(const uint4*)(bp0 + kbeg);
    uint4 b1 = *(const uint4*)(bp1 + kbeg);

    for (int i = 0; i < ITERS; ++i) {
        const int k0 = kbeg + i * BK;
        short* Ab = As[i & 1];
        short* Bb = Bs[i & 1];

        *(short8*)(Ab + w0) = bnrelu8(h0, sa, sb);
        *(short8*)(Ab + w1) = bnrelu8(h1, sa, sb);
        *(uint4*)(Bb + w0) = b0;
        *(uint4*)(Bb + w1) = b1;
        __syncthreads();   // lgkm-only drain (no global_load_lds in flight)

        const int kn = (i + 1 < ITERS) ? k0 + BK : kbeg;
        h0 = *(const uint4*)(hp0 + kn);
        h1 = *(const uint4*)(hp1 + kn);
        sa = *(const uint4*)(ssp + kn);
        sb = *(const uint4*)(ssp + kn + 4);
        b0 = *(const uint4*)(bp0 + kn);
        b1 = *(const uint4*)(bp1 + kn);

        short8 af[4], bfr[4];
#pragma unroll
        for (int mi = 0; mi < 4; ++mi) {
            int row = wr * 64 + mi * 16 + l15;
            af[mi] = *(const short8*)(Ab + row * BK + (swz(row, quad) << 3));
        }
#pragma unroll
        for (int ni = 0; ni < 4; ++ni) {
            int row = wc * 64 + ni * 16 + l15;
            bfr[ni] = *(const short8*)(Bb + row * BK + (swz(row, quad) << 3));
        }
#pragma unroll
        for (int mi = 0; mi < 4; ++mi)
#pragma unroll
            for (int ni = 0; ni < 4; ++ni)
                acc[mi][ni] = __builtin_amdgcn_mfma_f32_16x16x32_bf16(
                    af[mi], bfr[ni], acc[mi][ni], 0, 0, 0);
    }

#pragma unroll
    for (int mi = 0; mi < 4; ++mi)
#pragma unroll
        for (int ni = 0; ni < 4; ++ni)
#pragma unroll
            for (int r = 0; r < 4; ++r) {
                int row = m0 + wr * 64 + mi * 16 + quad * 4 + r;
                int col = n0 + wc * 64 + ni * 16 + l15;
                float v = acc[mi][ni][r];
                if (blockIdx.z == 0) v += bias[col];
                atomicAdd(&Cout[(size_t)row * N + col], v);
            }
}

// ---------------------------------------------------------------------------
// Row inverse-norms of 4 [B,256] f32 arrays. grid (B/4, 4), 1 wave/row.
__global__ void k_rownorm4(const float* __restrict__ a0, const float* __restrict__ a1,
                           const float* __restrict__ a2, const float* __restrict__ a3,
                           float* __restrict__ o0, float* __restrict__ o1,
                           float* __restrict__ o2, float* __restrict__ o3) {
    int which = blockIdx.y;
    const float* x = which == 0 ? a0 : which == 1 ? a1 : which == 2 ? a2 : a3;
    float* inv = which == 0 ? o0 : which == 1 ? o1 : which == 2 ? o2 : o3;
    int row = blockIdx.x * 4 + (threadIdx.x >> 6);
    int lane = threadIdx.x & 63;
    float4 v = ((const float4*)(x + (size_t)row * E_DIM))[lane];
    float s = v.x * v.x + v.y * v.y + v.z * v.z + v.w * v.w;
#pragma unroll
    for (int o = 32; o; o >>= 1) s += __shfl_down(s, o);
    if (lane == 0) inv[row] = 1.f / fmaxf(sqrtf(s), 1e-12f);
}

// ---------------------------------------------------------------------------
// Transpose + row-scale + cast: X [8192,256] f32, inv[8192] -> XT [256,8192] bf16
__global__ void k_tn_cast(
    const float* __restrict__ x0, const float* __restrict__ x1,
    const float* __restrict__ x2, const float* __restrict__ x3,
    const float* __restrict__ i0, const float* __restrict__ i1,
    const float* __restrict__ i2, const float* __restrict__ i3,
    unsigned short* __restrict__ o0, unsigned short* __restrict__ o1,
    unsigned short* __restrict__ o2, unsigned short* __restrict__ o3) {
    const int z = blockIdx.z;
    const float* x = z == 0 ? x0 : z == 1 ? x1 : z == 2 ? x2 : x3;
    const float* inv = z == 0 ? i0 : z == 1 ? i1 : z == 2 ? i2 : i3;
    unsigned short* out = z == 0 ? o0 : z == 1 ? o1 : z == 2 ? o2 : o3;

    __shared__ float tile[32][33];
    const int c0 = blockIdx.x * 32, r0 = blockIdx.y * 32;
    const int tx = threadIdx.x & 31, ty = threadIdx.x >> 5;
#pragma unroll
    for (int j = 0; j < 4; ++j) {
        int r = r0 + ty * 4 + j;
        tile[ty * 4 + j][tx] = x[(size_t)r * E_DIM + c0 + tx] * inv[r];
    }
    __syncthreads();
#pragma unroll
    for (int j = 0; j < 4; ++j)
        out[(size_t)(c0 + ty * 4 + j) * B_ROWS + r0 + tx] = f2b(tile[tx][ty * 4 + j]);
}

// ---------------------------------------------------------------------------
// Gram via MFMA: Mout[a,b] += sum_k AT[a,k]*BT[b,k], AT/BT bf16 [256,8192].
// BM=BN=64, BK=32, swizzled staging, split-K x16; grid (4,4,32).
#define GKS 16
__global__ __launch_bounds__(256) void k_gram(
    const unsigned short* __restrict__ p1T, const unsigned short* __restrict__ q2T,
    const unsigned short* __restrict__ p2T, const unsigned short* __restrict__ q1T,
    float* __restrict__ Ma, float* __restrict__ Mb) {
    constexpr int BK = 32;
    const int mec = blockIdx.z >> 4, kz = blockIdx.z & 15;
    const unsigned short* A = mec ? p2T : p1T;
    const unsigned short* Bt = mec ? q1T : q2T;
    float* Mout = mec ? Mb : Ma;

    __shared__ __align__(16) short As[64 * BK];
    __shared__ __align__(16) short Bs[64 * BK];

    const int t = threadIdx.x;
    const int lane = t & 63, wv = t >> 6;
    const int wr = wv >> 1, wc = wv & 1;
    const int l15 = lane & 15, quad = lane >> 4;
    const int m0 = blockIdx.y * 64, n0 = blockIdx.x * 64;
    const int kbeg = kz * (B_ROWS / GKS);

    f32x4 acc[2][2] = {};

    for (int k0 = kbeg; k0 < kbeg + B_ROWS / GKS; k0 += BK) {
        {
            int row = t >> 2, kc = swz(row, t & 3);
            const short* gpa = (const short*)A + (size_t)(m0 + row) * B_ROWS + k0 + kc * 8;
            short* lpa = As + (size_t)(wv << 6) * 8;
            __builtin_amdgcn_global_load_lds((gas1_t)gpa, (las3_t)lpa, 16, 0, 0);
            const short* gpb = (const short*)Bt + (size_t)(n0 + row) * B_ROWS + k0 + kc * 8;
            short* lpb = Bs + (size_t)(wv << 6) * 8;
            __builtin_amdgcn_global_load_lds((gas1_t)gpb, (las3_t)lpb, 16, 0, 0);
        }
        __syncthreads();

        short8 af[2], bfr[2];
#pragma unroll
        for (int mi = 0; mi < 2; ++mi) {
            int row = wr * 32 + mi * 16 + l15;
            af[mi] = *(const short8*)(As + row * BK + (swz(row, quad) << 3));
        }
#pragma unroll
        for (int ni = 0; ni < 2; ++ni) {
            int row = wc * 32 + ni * 16 + l15;
            bfr[ni] = *(const short8*)(Bs + row * BK + (swz(row, quad) << 3));
        }
#pragma unroll
        for (int mi = 0; mi < 2; ++mi)
#pragma unroll
            for (int ni = 0; ni < 2; ++ni)
                acc[mi][ni] = __builtin_amdgcn_mfma_f32_16x16x32_bf16(
                    af[mi], bfr[ni], acc[mi][ni], 0, 0, 0);
        __syncthreads();
    }

#pragma unroll
    for (int mi = 0; mi < 2; ++mi)
#pragma unroll
        for (int ni = 0; ni < 2; ++ni)
#pragma unroll
            for (int r = 0; r < 4; ++r) {
                int row = m0 + wr * 32 + mi * 16 + quad * 4 + r;
                int col = n0 + wc * 32 + ni * 16 + l15;
                atomicAdd(&Mout[(size_t)row * E_DIM + col], acc[mi][ni][r]);
            }
}

// M2 = M*M (256x256). grid (16,16,2) block 256.
__global__ void k_m2(const float* __restrict__ Ma, const float* __restrict__ Mb,
                     float* __restrict__ M2a, float* __restrict__ M2b) {
    const float* M = blockIdx.z ? Mb : Ma;
    float* M2 = blockIdx.z ? M2b : M2a;
    int b = blockIdx.x * 16 + (threadIdx.x & 15);
    int a = blockIdx.y * 16 + (threadIdx.x >> 4);
    float s = 0.f;
    for (int k = 0; k < E_DIM; ++k) s += M[a * E_DIM + k] * M[k * E_DIM + b];
    M2[a * E_DIM + b] = s;
}

// ---------------------------------------------------------------------------
// Traces, tiled multi-block: grid (8,8,2), block 256.
__global__ __launch_bounds__(256) void k_traces2(
    const float* __restrict__ Ma, const float* __restrict__ M2a,
    const float* __restrict__ Mb, const float* __restrict__ M2b,
    const float* __restrict__ lam, float* __restrict__ out) {
    const float* M  = blockIdx.z ? Mb  : Ma;
    const float* M2 = blockIdx.z ? M2b : M2a;
    const int i0 = blockIdx.y * 32, j0 = blockIdx.x * 32;
    const int t = threadIdx.x, col = t & 31, row = t >> 5;  // row 0..7

    __shared__ float A[32][33], Bt[32][33], A2[32][33], B2[32][33];
#pragma unroll
    for (int r = 0; r < 4; ++r) {
        int rr = r * 8 + row;
        A [rr][col] = M [(i0 + rr) * E_DIM + j0 + col];
        Bt[rr][col] = M [(j0 + rr) * E_DIM + i0 + col];
        A2[rr][col] = M2[(i0 + rr) * E_DIM + j0 + col];
        B2[rr][col] = M2[(j0 + rr) * E_DIM + i0 + col];
    }
    __syncthreads();

    float lamv = lam[0];
    float il = 1.f / lamv;
    float F = -0.5f * lamv * (1.f / B_ROWS);  // -0.5*lam/B
    float c1 = F * il;
    float c2 = -F * 0.5f * il * il;
    float c3 = F * (1.f / 3.f) * il * il * il;
    float c4 = -F * 0.25f * il * il * il * il;

    float s = 0.f;
#pragma unroll
    for (int r = 0; r < 4; ++r) {
        int rr = r * 8 + row;
        float mij = A[rr][col], mji = Bt[col][rr];
        float m2ij = A2[rr][col], m2ji = B2[col][rr];
        s += c2 * mij * mji + c3 * m2ij * mji + c4 * m2ij * m2ji;
        if (i0 + rr == j0 + col) s += c1 * mij;
    }
#pragma unroll
    for (int o = 32; o; o >>= 1) s += __shfl_down(s, o);
    __shared__ float red[4];
    if ((t & 63) == 0) red[t >> 6] = s;
    __syncthreads();
    if (t == 0) atomicAdd(out, red[0] + red[1] + red[2] + red[3]);
}

// ---------------------------------------------------------------------------
extern "C" void kernel_launch(void* const* d_in, const int* in_sizes, int n_in,
                              void* d_out, int out_size, void* d_ws, size_t ws_size,
                              hipStream_t stream) {
    const float* z1 = (const float*)d_in[0];
    const float* z2 = (const float*)d_in[1];
    const float* p1 = (const float*)d_in[2];
    const float* p2 = (const float*)d_in[3];
    const float* W1 = (const float*)d_in[4];
    const float* gamma = (const float*)d_in[5];
    const float* beta = (const float*)d_in[6];
    const float* W2 = (const float*)d_in[7];
    const float* b2 = (const float*)d_in[8];
    const float* lam = (const float*)d_in[9];
    float* out = (float*)d_out;
    char* ws = (char*)d_ws;

    // workspace layout (~89 MB)
    size_t off = 0;
    auto alloc = [&](size_t bytes) { size_t o = off; off += (bytes + 255) & ~(size_t)255; return o; };
    unsigned short* W1T = (unsigned short*)(ws + alloc((size_t)E_DIM * H_DIM * 2));  // [H,E] bf16
    unsigned short* W2T = (unsigned short*)(ws + alloc((size_t)H_DIM * E_DIM * 2));  // [E,H] bf16
    unsigned short* zb  = (unsigned short*)(ws + alloc((size_t)B_ROWS * E_DIM * 2));
    unsigned short* h   = (unsigned short*)(ws + alloc((size_t)B_ROWS * H_DIM * 2));
    float* q1 = (float*)(ws + alloc((size_t)B_ROWS * E_DIM * 4));
    float* q2 = (float*)(ws + alloc((size_t)B_ROWS * E_DIM * 4));
    float* colsum   = (float*)(ws + alloc(H_DIM * 4));
    float* colsumsq = (float*)(ws + alloc(H_DIM * 4));
    unsigned* ssb = (unsigned*)(ws + alloc(H_DIM * 4));
    float* invp1 = (float*)(ws + alloc(B_ROWS * 4));
    float* invp2 = (float*)(ws + alloc(B_ROWS * 4));
    float* invq1 = (float*)(ws + alloc(B_ROWS * 4));
    float* invq2 = (float*)(ws + alloc(B_ROWS * 4));
    float* Ma  = (float*)(ws + alloc((size_t)E_DIM * E_DIM * 4));
    float* Mb  = (float*)(ws + alloc((size_t)E_DIM * E_DIM * 4));
    float* M2a = (float*)(ws + alloc((size_t)E_DIM * E_DIM * 4));
    float* M2b = (float*)(ws + alloc((size_t)E_DIM * E_DIM * 4));

    // transposed normalized bf16 views alias into h (free after last GEMM2)
    const size_t TSZ = (size_t)E_DIM * B_ROWS;  // 2M elements each
    unsigned short* p1T = h;
    unsigned short* q2T = h + TSZ;
    unsigned short* p2T = h + 2 * TSZ;
    unsigned short* q1T = h + 3 * TSZ;

    // zero the accumulation targets (d_ws/d_out are poisoned before each call)
    hipMemsetAsync(out, 0, sizeof(float), stream);
    hipMemsetAsync(q1, 0, (size_t)2 * B_ROWS * E_DIM * sizeof(float), stream);  // q1+q2 contiguous

    // weight transposes (k-contiguous operands for MFMA)
    k_transpose_cast<<<dim3(H_DIM / 32, E_DIM / 32), 256, 0, stream>>>(W1, W1T, E_DIM, H_DIM);
    k_transpose_cast<<<dim3(E_DIM / 32, H_DIM / 32), 256, 0, stream>>>(W2, W2T, H_DIM, E_DIM);

    const float* zs[2] = {z1, z2};
    float* qs[2] = {q1, q2};
    for (int v = 0; v < 2; ++v) {
        k_cast_bf16<<<dim3(B_ROWS * E_DIM / 4 / 256), 256, 0, stream>>>(zs[v], zb, B_ROWS * E_DIM / 4);
        hipMemsetAsync(colsum, 0, H_DIM * 2 * sizeof(float), stream);  // colsum+colsumsq contiguous
        // h = z @ W1, with fused column stats
        k_gemm1<<<dim3(H_DIM / 128, B_ROWS / 128), 256, 0, stream>>>(
            zb, W1T, h, colsum, colsumsq, B_ROWS, H_DIM, E_DIM);
        k_bnprep<<<dim3(H_DIM / 256), 256, 0, stream>>>(colsum, colsumsq, gamma, beta, ssb);
        // q = relu(bn(h)) @ W2 + b2 — 128x128 register-dbuf, split-K x8
        k_gemm2r<<<dim3(E_DIM / 128, B_ROWS / 128, 8), 256, 0, stream>>>(
            h, W2T, qs[v], b2, ssb, B_ROWS, E_DIM, H_DIM);
    }

    k_rownorm4<<<dim3(B_ROWS / 4, 4), 256, 0, stream>>>(p1, p2, q1, q2, invp1, invp2, invq1, invq2);

    // transposed, row-normalized, bf16 copies of p1,q2,p2,q1 (into h's space)
    k_tn_cast<<<dim3(E_DIM / 32, B_ROWS / 32, 4), 256, 0, stream>>>(
        p1, q2, p2, q1, invp1, invq2, invp2, invq1, p1T, q2T, p2T, q1T);

    hipMemsetAsync(Ma, 0, (size_t)E_DIM * E_DIM * 2 * sizeof(float), stream);  // Ma+Mb contiguous
    k_gram<<<dim3(4, 4, 2 * GKS), 256, 0, stream>>>(p1T, q2T, p2T, q1T, Ma, Mb);
    k_m2<<<dim3(16, 16, 2), 256, 0, stream>>>(Ma, Mb, M2a, M2b);
    k_traces2<<<dim3(8, 8, 2), 256, 0, stream>>>(Ma, M2a, Mb, M2b, lam, out);
}

// Round 14
// 374.809 us; speedup vs baseline: 1.0522x; 1.0522x over previous
//
#include <hip/hip_runtime.h>

// Problem constants (fixed by reference)
#define B_ROWS 8192
#define E_DIM  256
#define H_DIM  4096

typedef __attribute__((ext_vector_type(8))) short short8;
typedef __attribute__((ext_vector_type(4))) float f32x4;

typedef __attribute__((address_space(1))) const void* gas1_t;
typedef __attribute__((address_space(3))) void*       las3_t;

__device__ __forceinline__ float b2f(unsigned short s) {
    return __uint_as_float(((unsigned)s) << 16);
}
__device__ __forceinline__ unsigned short f2b(float f) {
    unsigned u = __float_as_uint(f);
    u += 0x7fffu + ((u >> 16) & 1u);   // RNE
    return (unsigned short)(u >> 16);
}

// LDS swizzle for BK=32 (64B rows, 4x16B slots): slot' = slot ^ ((row>>1)&3)
__device__ __forceinline__ int swz(int row, int slot) {
    return slot ^ ((row >> 1) & 3);
}

__device__ __forceinline__ short8 pack8(float4 a, float4 b) {
    short8 o;
    o[0] = (short)f2b(a.x); o[1] = (short)f2b(a.y);
    o[2] = (short)f2b(a.z); o[3] = (short)f2b(a.w);
    o[4] = (short)f2b(b.x); o[5] = (short)f2b(b.y);
    o[6] = (short)f2b(b.z); o[7] = (short)f2b(b.w);
    return o;
}

// ---------------------------------------------------------------------------
// Transpose + cast f32 [R,C] -> bf16 [C,R]
__global__ void k_transpose_cast(const float* __restrict__ in,
                                 unsigned short* __restrict__ out,
                                 int R, int C) {
    __shared__ float tile[32][33];
    const int c0 = blockIdx.x * 32, r0 = blockIdx.y * 32;
    const int tx = threadIdx.x & 31, ty = threadIdx.x >> 5;  // ty 0..7
#pragma unroll
    for (int j = 0; j < 4; ++j)
        tile[ty * 4 + j][tx] = in[(size_t)(r0 + ty * 4 + j) * C + c0 + tx];
    __syncthreads();
#pragma unroll
    for (int j = 0; j < 4; ++j)
        out[(size_t)(c0 + ty * 4 + j) * R + r0 + tx] = f2b(tile[tx][ty * 4 + j]);
}

// ---------------------------------------------------------------------------
// GEMM1 big-K (R14): h[M,4096] = cast_bf16(Z[M,256]) @ W1T[4096,256]^T
// + fused z-cast + column sum/sumsq. 128x128 tile; the FULL K=256 handled as
// two 128-halves in single-buffered 64KB LDS -> 3 barriers total, 64
// MFMA/wave per half. A: f32 load + cast in registers -> ds_write. B: DMA
// via global_load_lds. LDS rows = 16 chunks of 16B, chunk swizzled by
// (row&7) -> even bank distribution (BW floor, no hot bank).
// grid (H/128=32, M/128=64) = 2048 blocks, 2 blocks/CU (64KB LDS).
__global__ __launch_bounds__(256) void k_gemm1b(
    const float* __restrict__ Z, const unsigned short* __restrict__ Bt,
    unsigned short* __restrict__ Hout,
    float* __restrict__ cs, float* __restrict__ cs2) {
    constexpr int K = E_DIM;      // 256
    constexpr int KC = 128;       // half staged per phase; 16 chunks/row
    __shared__ __align__(16) short As[128 * KC];  // 32 KB
    __shared__ __align__(16) short Bs[128 * KC];  // 32 KB

    const int t = threadIdx.x;
    const int lane = t & 63, wv = t >> 6;
    const int wr = wv >> 1, wc = wv & 1;
    const int l15 = lane & 15, quad = lane >> 4;
    const int m0 = blockIdx.y * 128, n0 = blockIdx.x * 128;

    f32x4 acc[4][4] = {};

#pragma unroll
    for (int half = 0; half < 2; ++half) {
        const int kh = half * KC;
        if (half) __syncthreads();   // WAR: previous compute done before restage

        // B panel: 128 rows x 16 chunks = 2048 chunks -> 8 DMA insts/thread
#pragma unroll
        for (int i = 0; i < 8; ++i) {
            int u = i * 256 + t;
            int row = u >> 4, pos = u & 15;
            int c = pos ^ (row & 7);   // slot 'pos' holds global chunk c
            const short* gp = (const short*)Bt + (size_t)(n0 + row) * K + kh + c * 8;
            short* lp = Bs + (size_t)(i * 256 + (wv << 6)) * 8;  // wave-uniform base
            __builtin_amdgcn_global_load_lds((gas1_t)gp, (las3_t)lp, 16, 0, 0);
        }
        // A panel: f32 -> bf16 via registers, 8 chunks/thread (2 threads/row)
        {
            int row = t >> 1;
            int cbase = (t & 1) * 8;
#pragma unroll
            for (int j = 0; j < 8; ++j) {
                int c = cbase + j;
                const float* zp = Z + (size_t)(m0 + row) * K + kh + c * 8;
                float4 a = *(const float4*)zp;
                float4 b = *(const float4*)(zp + 4);
                *(short8*)(As + row * KC + ((c ^ (row & 7)) << 3)) = pack8(a, b);
            }
        }
        __syncthreads();   // drains B DMA (vmcnt) + A ds_writes (lgkm), once per half

        // compute: 4 k-steps x 16 MFMA/wave, zero barriers
#pragma unroll
        for (int s = 0; s < 4; ++s) {
            int cc = s * 4 + quad;
            short8 af[4], bfr[4];
#pragma unroll
            for (int mi = 0; mi < 4; ++mi) {
                int row = wr * 64 + mi * 16 + l15;
                af[mi] = *(const short8*)(As + row * KC + ((cc ^ (row & 7)) << 3));
            }
#pragma unroll
            for (int ni = 0; ni < 4; ++ni) {
                int row = wc * 64 + ni * 16 + l15;
                bfr[ni] = *(const short8*)(Bs + row * KC + ((cc ^ (row & 7)) << 3));
            }
#pragma unroll
            for (int mi = 0; mi < 4; ++mi)
#pragma unroll
                for (int ni = 0; ni < 4; ++ni)
                    acc[mi][ni] = __builtin_amdgcn_mfma_f32_16x16x32_bf16(
                        af[mi], bfr[ni], acc[mi][ni], 0, 0, 0);
        }
    }

    // epilogue: C/D layout col=lane&15, row=quad*4+reg (measured m89)
#pragma unroll
    for (int ni = 0; ni < 4; ++ni) {
        float s = 0.f, s2 = 0.f;
#pragma unroll
        for (int mi = 0; mi < 4; ++mi)
#pragma unroll
            for (int r = 0; r < 4; ++r) {
                int row = m0 + wr * 64 + mi * 16 + quad * 4 + r;
                int col = n0 + wc * 64 + ni * 16 + l15;
                float v = acc[mi][ni][r];
                Hout[(size_t)row * H_DIM + col] = f2b(v);
                s += v; s2 += v * v;
            }
        s  += __shfl_xor(s, 16);  s  += __shfl_xor(s, 32);
        s2 += __shfl_xor(s2, 16); s2 += __shfl_xor(s2, 32);
        if (quad == 0) {
            int col = n0 + wc * 64 + ni * 16 + l15;
            atomicAdd(&cs[col], s);
            atomicAdd(&cs2[col], s2);
        }
    }
}

// BN scale/shift packed as bf16 pair: ssb[k] = f2b(scale)<<16 | f2b(shift)
// (bf16 params verified numerically R6/R9/R10: absmax 7.6e-6 vs 2e-5 thr)
__global__ void k_bnprep(const float* __restrict__ sum, const float* __restrict__ sumsq,
                         const float* __restrict__ gamma, const float* __restrict__ beta,
                         unsigned* __restrict__ ssb) {
    int j = blockIdx.x * 256 + threadIdx.x;
    float mu = sum[j] * (1.f / B_ROWS);
    float var = sumsq[j] * (1.f / B_ROWS) - mu * mu;
    float sc = gamma[j] * rsqrtf(var + 1e-5f);
    float sh = beta[j] - mu * sc;
    ssb[j] = ((unsigned)f2b(sc) << 16) | (unsigned)f2b(sh);
}

__device__ __forceinline__ short8 bnrelu8(uint4 hv, uint4 sa, uint4 sb) {
    const unsigned short* hu = (const unsigned short*)&hv;
    const unsigned* wa = (const unsigned*)&sa;
    const unsigned* wb = (const unsigned*)&sb;
    short8 o;
#pragma unroll
    for (int j = 0; j < 8; ++j) {
        unsigned w = j < 4 ? wa[j] : wb[j - 4];
        float sc = __uint_as_float(w & 0xffff0000u);
        float sh = __uint_as_float(w << 16);
        float v = fmaxf(b2f(hu[j]) * sc + sh, 0.f);
        o[j] = (short)f2b(v);
    }
    return o;
}

// ---------------------------------------------------------------------------
// GEMM2 (R10's winning version, verbatim): register-staged DOUBLE-BUFFERED,
// lgkm-only barriers. q[M,N] += relu(bn(h))[M,K] * W2T[N,K]^T.
// BM=64, BN=128, BK=32, split-K x4.
__global__ __launch_bounds__(256) void k_gemm2d(
    const unsigned short* __restrict__ A, const unsigned short* __restrict__ Bt,
    float* __restrict__ Cout, const float* __restrict__ bias,
    const unsigned* __restrict__ ssb,
    int M, int N, int K) {
    constexpr int BK = 32, BM = 64, BN = 128;
    constexpr int MI = 2, NI = 4;
    __shared__ __align__(16) short As[2][BM * BK];   // 2 x 4 KB
    __shared__ __align__(16) short Bs[2][BN * BK];   // 2 x 8 KB

    const int t = threadIdx.x;
    const int lane = t & 63, wv = t >> 6;
    const int wr = wv >> 1, wc = wv & 1;
    const int l15 = lane & 15, quad = lane >> 4;
    const int m0 = blockIdx.y * BM, n0 = blockIdx.x * BN;

    const int Kc = K / gridDim.z;
    const int kbeg = blockIdx.z * Kc;
    const int ITERS = Kc / BK;

    const int arow = t >> 2, akc = t & 3;
    const unsigned short* hp = A + (size_t)(m0 + arow) * K + akc * 8;
    const unsigned* ssp = ssb + akc * 8;
    const int awoff = arow * BK + (swz(arow, akc) << 3);

    const unsigned short* bp0 = Bt + (size_t)(n0 + arow) * K + akc * 8;
    const unsigned short* bp1 = Bt + (size_t)(n0 + 64 + arow) * K + akc * 8;
    const int bwoff0 = arow * BK + (swz(arow, akc) << 3);
    const int bwoff1 = (64 + arow) * BK + (swz(64 + arow, akc) << 3);

    f32x4 acc[MI][NI] = {};

    uint4 hreg = *(const uint4*)(hp + kbeg);
    uint4 sa = *(const uint4*)(ssp + kbeg);
    uint4 sb = *(const uint4*)(ssp + kbeg + 4);
    uint4 b0 = *(const uint4*)(bp0 + kbeg);
    uint4 b1 = *(const uint4*)(bp1 + kbeg);

    for (int i = 0; i < ITERS; ++i) {
        const int k0 = kbeg + i * BK;
        short* Ab = As[i & 1];
        short* Bb = Bs[i & 1];

        *(short8*)(Ab + awoff) = bnrelu8(hreg, sa, sb);
        *(uint4*)(Bb + bwoff0) = b0;
        *(uint4*)(Bb + bwoff1) = b1;
        __syncthreads();   // lgkm-only drain

        const int kn = (i + 1 < ITERS) ? k0 + BK : kbeg;
        hreg = *(const uint4*)(hp + kn);
        sa = *(const uint4*)(ssp + kn);
        sb = *(const uint4*)(ssp + kn + 4);
        b0 = *(const uint4*)(bp0 + kn);
        b1 = *(const uint4*)(bp1 + kn);

        short8 af[MI], bfr[NI];
#pragma unroll
        for (int mi = 0; mi < MI; ++mi) {
            int row = wr * 32 + mi * 16 + l15;
            af[mi] = *(const short8*)(Ab + row * BK + (swz(row, quad) << 3));
        }
#pragma unroll
        for (int ni = 0; ni < NI; ++ni) {
            int row = wc * 64 + ni * 16 + l15;
            bfr[ni] = *(const short8*)(Bb + row * BK + (swz(row, quad) << 3));
        }
#pragma unroll
        for (int mi = 0; mi < MI; ++mi)
#pragma unroll
            for (int ni = 0; ni < NI; ++ni)
                acc[mi][ni] = __builtin_amdgcn_mfma_f32_16x16x32_bf16(
                    af[mi], bfr[ni], acc[mi][ni], 0, 0, 0);
    }

#pragma unroll
    for (int mi = 0; mi < MI; ++mi)
#pragma unroll
        for (int ni = 0; ni < NI; ++ni)
#pragma unroll
            for (int r = 0; r < 4; ++r) {
                int row = m0 + wr * 32 + mi * 16 + quad * 4 + r;
                int col = n0 + wc * 64 + ni * 16 + l15;
                float v = acc[mi][ni][r];
                if (blockIdx.z == 0) v += bias[col];
                atomicAdd(&Cout[(size_t)row * N + col], v);
            }
}

// ---------------------------------------------------------------------------
// Fused norm + transpose + cast (replaces rownorm4 + tn_cast):
// per 32-row slab of X [8192,256] f32: load to LDS, compute row inv-norms,
// write XT [256,8192] bf16 normalized. grid (B/32, 4), block 256.
__global__ __launch_bounds__(256) void k_ntc(
    const float* __restrict__ x0, const float* __restrict__ x1,
    const float* __restrict__ x2, const float* __restrict__ x3,
    unsigned short* __restrict__ o0, unsigned short* __restrict__ o1,
    unsigned short* __restrict__ o2, unsigned short* __restrict__ o3) {
    const int z = blockIdx.y;
    const float* x = z == 0 ? x0 : z == 1 ? x1 : z == 2 ? x2 : x3;
    unsigned short* out = z == 0 ? o0 : z == 1 ? o1 : z == 2 ? o2 : o3;

    __shared__ float tile[32][264];   // stride 264 f -> 16B-aligned rows, 2-way banks
    __shared__ float red[32][8];
    __shared__ float invs[32];
    const int t = threadIdx.x;
    const int r0 = blockIdx.x * 32;

    // load 32x256 f32 slab (8 float4 per thread, coalesced)
#pragma unroll
    for (int i = 0; i < 8; ++i) {
        int u = i * 256 + t;                  // float4 index (2048 total)
        int row = u >> 6, cp = (u & 63) * 4;
        float4 v = *(const float4*)(x + (size_t)(r0 + row) * E_DIM + cp);
        *(float4*)&tile[row][cp] = v;
    }
    __syncthreads();
    // row sumsq partials
    {
        int row = t >> 3, cg = (t & 7) * 32;
        float s = 0.f;
#pragma unroll
        for (int j = 0; j < 32; ++j) { float v = tile[row][cg + j]; s += v * v; }
        red[row][t & 7] = s;
    }
    __syncthreads();
    if (t < 32) {
        float s = 0.f;
#pragma unroll
        for (int j = 0; j < 8; ++j) s += red[t][j];
        invs[t] = 1.f / fmaxf(sqrtf(s), 1e-12f);
    }
    __syncthreads();
    // transposed normalized write: lane = row (coalesced over output rows)
    {
        int row = t & 31, cb = (t >> 5) * 32;
        float inv = invs[row];
#pragma unroll
        for (int j = 0; j < 32; ++j) {
            int c = cb + j;
            out[(size_t)c * B_ROWS + r0 + row] = f2b(tile[row][c] * inv);
        }
    }
}

// ---------------------------------------------------------------------------
// Gram via MFMA: Mout[a,b] += sum_k AT[a,k]*BT[b,k], AT/BT bf16 [256,8192].
// BM=BN=64, BK=32, swizzled staging, split-K x16; grid (4,4,32).
#define GKS 16
__global__ __launch_bounds__(256) void k_gram(
    const unsigned short* __restrict__ p1T, const unsigned short* __restrict__ q2T,
    const unsigned short* __restrict__ p2T, const unsigned short* __restrict__ q1T,
    float* __restrict__ Ma, float* __restrict__ Mb) {
    constexpr int BK = 32;
    const int mec = blockIdx.z >> 4, kz = blockIdx.z & 15;
    const unsigned short* A = mec ? p2T : p1T;
    const unsigned short* Bt = mec ? q1T : q2T;
    float* Mout = mec ? Mb : Ma;

    __shared__ __align__(16) short As[64 * BK];
    __shared__ __align__(16) short Bs[64 * BK];

    const int t = threadIdx.x;
    const int lane = t & 63, wv = t >> 6;
    const int wr = wv >> 1, wc = wv & 1;
    const int l15 = lane & 15, quad = lane >> 4;
    const int m0 = blockIdx.y * 64, n0 = blockIdx.x * 64;
    const int kbeg = kz * (B_ROWS / GKS);

    f32x4 acc[2][2] = {};

    for (int k0 = kbeg; k0 < kbeg + B_ROWS / GKS; k0 += BK) {
        {
            int row = t >> 2, kc = swz(row, t & 3);
            const short* gpa = (const short*)A + (size_t)(m0 + row) * B_ROWS + k0 + kc * 8;
            short* lpa = As + (size_t)(wv << 6) * 8;
            __builtin_amdgcn_global_load_lds((gas1_t)gpa, (las3_t)lpa, 16, 0, 0);
            const short* gpb = (const short*)Bt + (size_t)(n0 + row) * B_ROWS + k0 + kc * 8;
            short* lpb = Bs + (size_t)(wv << 6) * 8;
            __builtin_amdgcn_global_load_lds((gas1_t)gpb, (las3_t)lpb, 16, 0, 0);
        }
        __syncthreads();

        short8 af[2], bfr[2];
#pragma unroll
        for (int mi = 0; mi < 2; ++mi) {
            int row = wr * 32 + mi * 16 + l15;
            af[mi] = *(const short8*)(As + row * BK + (swz(row, quad) << 3));
        }
#pragma unroll
        for (int ni = 0; ni < 2; ++ni) {
            int row = wc * 32 + ni * 16 + l15;
            bfr[ni] = *(const short8*)(Bs + row * BK + (swz(row, quad) << 3));
        }
#pragma unroll
        for (int mi = 0; mi < 2; ++mi)
#pragma unroll
            for (int ni = 0; ni < 2; ++ni)
                acc[mi][ni] = __builtin_amdgcn_mfma_f32_16x16x32_bf16(
                    af[mi], bfr[ni], acc[mi][ni], 0, 0, 0);
        __syncthreads();
    }

#pragma unroll
    for (int mi = 0; mi < 2; ++mi)
#pragma unroll
        for (int ni = 0; ni < 2; ++ni)
#pragma unroll
            for (int r = 0; r < 4; ++r) {
                int row = m0 + wr * 32 + mi * 16 + quad * 4 + r;
                int col = n0 + wc * 32 + ni * 16 + l15;
                atomicAdd(&Mout[(size_t)row * E_DIM + col], acc[mi][ni][r]);
            }
}

// M2 = M*M (256x256). grid (16,16,2) block 256.
__global__ void k_m2(const float* __restrict__ Ma, const float* __restrict__ Mb,
                     float* __restrict__ M2a, float* __restrict__ M2b) {
    const float* M = blockIdx.z ? Mb : Ma;
    float* M2 = blockIdx.z ? M2b : M2a;
    int b = blockIdx.x * 16 + (threadIdx.x & 15);
    int a = blockIdx.y * 16 + (threadIdx.x >> 4);
    float s = 0.f;
    for (int k = 0; k < E_DIM; ++k) s += M[a * E_DIM + k] * M[k * E_DIM + b];
    M2[a * E_DIM + b] = s;
}

// ---------------------------------------------------------------------------
// Traces, tiled multi-block: grid (8,8,2), block 256.
__global__ __launch_bounds__(256) void k_traces2(
    const float* __restrict__ Ma, const float* __restrict__ M2a,
    const float* __restrict__ Mb, const float* __restrict__ M2b,
    const float* __restrict__ lam, float* __restrict__ out) {
    const float* M  = blockIdx.z ? Mb  : Ma;
    const float* M2 = blockIdx.z ? M2b : M2a;
    const int i0 = blockIdx.y * 32, j0 = blockIdx.x * 32;
    const int t = threadIdx.x, col = t & 31, row = t >> 5;  // row 0..7

    __shared__ float A[32][33], Bt[32][33], A2[32][33], B2[32][33];
#pragma unroll
    for (int r = 0; r < 4; ++r) {
        int rr = r * 8 + row;
        A [rr][col] = M [(i0 + rr) * E_DIM + j0 + col];
        Bt[rr][col] = M [(j0 + rr) * E_DIM + i0 + col];
        A2[rr][col] = M2[(i0 + rr) * E_DIM + j0 + col];
        B2[rr][col] = M2[(j0 + rr) * E_DIM + i0 + col];
    }
    __syncthreads();

    float lamv = lam[0];
    float il = 1.f / lamv;
    float F = -0.5f * lamv * (1.f / B_ROWS);  // -0.5*lam/B
    float c1 = F * il;
    float c2 = -F * 0.5f * il * il;
    float c3 = F * (1.f / 3.f) * il * il * il;
    float c4 = -F * 0.25f * il * il * il * il;

    float s = 0.f;
#pragma unroll
    for (int r = 0; r < 4; ++r) {
        int rr = r * 8 + row;
        float mij = A[rr][col], mji = Bt[col][rr];
        float m2ij = A2[rr][col], m2ji = B2[col][rr];
        s += c2 * mij * mji + c3 * m2ij * mji + c4 * m2ij * m2ji;
        if (i0 + rr == j0 + col) s += c1 * mij;
    }
#pragma unroll
    for (int o = 32; o; o >>= 1) s += __shfl_down(s, o);
    __shared__ float red[4];
    if ((t & 63) == 0) red[t >> 6] = s;
    __syncthreads();
    if (t == 0) atomicAdd(out, red[0] + red[1] + red[2] + red[3]);
}

// ---------------------------------------------------------------------------
extern "C" void kernel_launch(void* const* d_in, const int* in_sizes, int n_in,
                              void* d_out, int out_size, void* d_ws, size_t ws_size,
                              hipStream_t stream) {
    const float* z1 = (const float*)d_in[0];
    const float* z2 = (const float*)d_in[1];
    const float* p1 = (const float*)d_in[2];
    const float* p2 = (const float*)d_in[3];
    const float* W1 = (const float*)d_in[4];
    const float* gamma = (const float*)d_in[5];
    const float* beta = (const float*)d_in[6];
    const float* W2 = (const float*)d_in[7];
    const float* b2 = (const float*)d_in[8];
    const float* lam = (const float*)d_in[9];
    float* out = (float*)d_out;
    char* ws = (char*)d_ws;

    // workspace layout (~85 MB)
    size_t off = 0;
    auto alloc = [&](size_t bytes) { size_t o = off; off += (bytes + 255) & ~(size_t)255; return o; };
    unsigned short* W1T = (unsigned short*)(ws + alloc((size_t)E_DIM * H_DIM * 2));  // [H,E] bf16
    unsigned short* W2T = (unsigned short*)(ws + alloc((size_t)H_DIM * E_DIM * 2));  // [E,H] bf16
    unsigned short* h   = (unsigned short*)(ws + alloc((size_t)B_ROWS * H_DIM * 2));
    // q1,q2,Ma,Mb contiguous -> single memset
    float* q1 = (float*)(ws + alloc((size_t)B_ROWS * E_DIM * 4));
    float* q2 = (float*)(ws + alloc((size_t)B_ROWS * E_DIM * 4));
    float* Ma  = (float*)(ws + alloc((size_t)E_DIM * E_DIM * 4));
    float* Mb  = (float*)(ws + alloc((size_t)E_DIM * E_DIM * 4));
    float* M2a = (float*)(ws + alloc((size_t)E_DIM * E_DIM * 4));
    float* M2b = (float*)(ws + alloc((size_t)E_DIM * E_DIM * 4));
    // two colsum sets (one per view), contiguous -> single memset
    float* cs0 = (float*)(ws + alloc(H_DIM * 4));
    float* cs0q = (float*)(ws + alloc(H_DIM * 4));
    float* cs1 = (float*)(ws + alloc(H_DIM * 4));
    float* cs1q = (float*)(ws + alloc(H_DIM * 4));
    unsigned* ssb = (unsigned*)(ws + alloc(H_DIM * 4));

    // transposed normalized bf16 views alias into h (free after last GEMM2)
    const size_t TSZ = (size_t)E_DIM * B_ROWS;  // 2M elements each
    unsigned short* p1T = h;
    unsigned short* q2T = h + TSZ;
    unsigned short* p2T = h + 2 * TSZ;
    unsigned short* q1T = h + 3 * TSZ;

    // zero accumulation targets (3 memsets total)
    hipMemsetAsync(out, 0, sizeof(float), stream);
    hipMemsetAsync(q1, 0, ((size_t)2 * B_ROWS * E_DIM + 2 * E_DIM * E_DIM) * 4, stream);
    hipMemsetAsync(cs0, 0, (size_t)4 * H_DIM * 4, stream);

    // weight transposes (k-contiguous operands for MFMA)
    k_transpose_cast<<<dim3(H_DIM / 32, E_DIM / 32), 256, 0, stream>>>(W1, W1T, E_DIM, H_DIM);
    k_transpose_cast<<<dim3(E_DIM / 32, H_DIM / 32), 256, 0, stream>>>(W2, W2T, H_DIM, E_DIM);

    const float* zs[2] = {z1, z2};
    float* qs[2] = {q1, q2};
    float* css[2] = {cs0, cs1};
    float* cssq[2] = {cs0q, cs1q};
    for (int v = 0; v < 2; ++v) {
        // h = cast(z) @ W1, fused cast + colstats, big-K 3-barrier structure
        k_gemm1b<<<dim3(H_DIM / 128, B_ROWS / 128), 256, 0, stream>>>(
            zs[v], W1T, h, css[v], cssq[v]);
        k_bnprep<<<dim3(H_DIM / 256), 256, 0, stream>>>(css[v], cssq[v], gamma, beta, ssb);
        // q = relu(bn(h)) @ W2 + b2 — R10's dbuf register staging, split-K x4
        k_gemm2d<<<dim3(E_DIM / 128, B_ROWS / 64, 4), 256, 0, stream>>>(
            h, W2T, qs[v], b2, ssb, B_ROWS, E_DIM, H_DIM);
    }

    // fused row-norm + transpose + cast of p1,q2,p2,q1 (into h's space)
    k_ntc<<<dim3(B_ROWS / 32, 4), 256, 0, stream>>>(
        p1, q2, p2, q1, p1T, q2T, p2T, q1T);

    k_gram<<<dim3(4, 4, 2 * GKS), 256, 0, stream>>>(p1T, q2T, p2T, q1T, Ma, Mb);
    k_m2<<<dim3(16, 16, 2), 256, 0, stream>>>(Ma, Mb, M2a, M2b);
    k_traces2<<<dim3(8, 8, 2), 256, 0, stream>>>(Ma, M2a, Mb, M2b, lam, out);
}

// Round 15
// 334.321 us; speedup vs baseline: 1.1797x; 1.1211x over previous
//
#include <hip/hip_runtime.h>

// Problem constants (fixed by reference)
#define B_ROWS 8192
#define E_DIM  256
#define H_DIM  4096

typedef __attribute__((ext_vector_type(8))) short short8;
typedef __attribute__((ext_vector_type(4))) float f32x4;

typedef __attribute__((address_space(1))) const void* gas1_t;
typedef __attribute__((address_space(3))) void*       las3_t;

__device__ __forceinline__ float b2f(unsigned short s) {
    return __uint_as_float(((unsigned)s) << 16);
}
__device__ __forceinline__ unsigned short f2b(float f) {
    unsigned u = __float_as_uint(f);
    u += 0x7fffu + ((u >> 16) & 1u);   // RNE
    return (unsigned short)(u >> 16);
}

// LDS swizzle for BK=32 (64B rows, 4x16B slots): slot' = slot ^ ((row>>1)&3)
// -> ds_read_b128 fragment reads are 2-way (free, m136) instead of 8-way.
__device__ __forceinline__ int swz(int row, int slot) {
    return slot ^ ((row >> 1) & 3);
}

// ---------------------------------------------------------------------------
// Transpose + cast f32 [R,C] -> bf16 [C,R]
__global__ void k_transpose_cast(const float* __restrict__ in,
                                 unsigned short* __restrict__ out,
                                 int R, int C) {
    __shared__ float tile[32][33];
    const int c0 = blockIdx.x * 32, r0 = blockIdx.y * 32;
    const int tx = threadIdx.x & 31, ty = threadIdx.x >> 5;  // ty 0..7
#pragma unroll
    for (int j = 0; j < 4; ++j)
        tile[ty * 4 + j][tx] = in[(size_t)(r0 + ty * 4 + j) * C + c0 + tx];
    __syncthreads();
#pragma unroll
    for (int j = 0; j < 4; ++j)
        out[(size_t)(c0 + ty * 4 + j) * R + r0 + tx] = f2b(tile[tx][ty * 4 + j]);
}

// ---------------------------------------------------------------------------
// Cast f32 -> bf16, 4 elems/thread.
__global__ void k_cast_bf16(const float* __restrict__ in,
                            unsigned short* __restrict__ out, int n4) {
    int i = blockIdx.x * blockDim.x + threadIdx.x;
    if (i < n4) {
        float4 v = ((const float4*)in)[i];
        ushort4 o;
        o.x = f2b(v.x); o.y = f2b(v.y); o.z = f2b(v.z); o.w = f2b(v.w);
        ((ushort4*)out)[i] = o;
    }
}

// ---------------------------------------------------------------------------
// GEMM1 (R10 proven): h[M,N] = A[M,K] * Bt[N,K]^T, bf16 out + fused col stats.
// BM=BN=128, BK=32, swizzled global_load_lds staging. grid (N/128, M/128).
__global__ __launch_bounds__(256) void k_gemm1(
    const unsigned short* __restrict__ A, const unsigned short* __restrict__ Bt,
    unsigned short* __restrict__ Cout,
    float* __restrict__ cs, float* __restrict__ cs2,
    int M, int N, int K) {
    constexpr int BK = 32, BM = 128, BN = 128;
    constexpr int MI = 4, NI = 4;
    __shared__ __align__(16) short As[BM * BK];
    __shared__ __align__(16) short Bs[BN * BK];

    const int t = threadIdx.x;
    const int lane = t & 63, wv = t >> 6;
    const int wr = wv >> 1, wc = wv & 1;
    const int l15 = lane & 15, quad = lane >> 4;
    const int m0 = blockIdx.y * BM, n0 = blockIdx.x * BN;

    f32x4 acc[MI][NI] = {};

    for (int k0 = 0; k0 < K; k0 += BK) {
#pragma unroll
        for (int q = 0; q < 2; ++q) {
            int u = q * 256 + t;
            int row = u >> 2, kc = swz(row, u & 3);
            const short* gp = (const short*)A + (size_t)(m0 + row) * K + k0 + kc * 8;
            short* lp = As + (size_t)(q * 256 + (wv << 6)) * 8;  // wave-uniform base
            __builtin_amdgcn_global_load_lds((gas1_t)gp, (las3_t)lp, 16, 0, 0);
        }
#pragma unroll
        for (int q = 0; q < 2; ++q) {
            int u = q * 256 + t;
            int row = u >> 2, kc = swz(row, u & 3);
            const short* gp = (const short*)Bt + (size_t)(n0 + row) * K + k0 + kc * 8;
            short* lp = Bs + (size_t)(q * 256 + (wv << 6)) * 8;
            __builtin_amdgcn_global_load_lds((gas1_t)gp, (las3_t)lp, 16, 0, 0);
        }
        __syncthreads();

        short8 af[MI], bfr[NI];
#pragma unroll
        for (int mi = 0; mi < MI; ++mi) {
            int row = wr * 64 + mi * 16 + l15;
            af[mi] = *(const short8*)(As + row * BK + (swz(row, quad) << 3));
        }
#pragma unroll
        for (int ni = 0; ni < NI; ++ni) {
            int row = wc * 64 + ni * 16 + l15;
            bfr[ni] = *(const short8*)(Bs + row * BK + (swz(row, quad) << 3));
        }
#pragma unroll
        for (int mi = 0; mi < MI; ++mi)
#pragma unroll
            for (int ni = 0; ni < NI; ++ni)
                acc[mi][ni] = __builtin_amdgcn_mfma_f32_16x16x32_bf16(
                    af[mi], bfr[ni], acc[mi][ni], 0, 0, 0);
        __syncthreads();
    }

    // epilogue: C/D layout col=lane&15, row=quad*4+reg (measured m89)
#pragma unroll
    for (int ni = 0; ni < NI; ++ni) {
        float s = 0.f, s2 = 0.f;
#pragma unroll
        for (int mi = 0; mi < MI; ++mi)
#pragma unroll
            for (int r = 0; r < 4; ++r) {
                int row = m0 + wr * 64 + mi * 16 + quad * 4 + r;
                int col = n0 + wc * 64 + ni * 16 + l15;
                float v = acc[mi][ni][r];
                Cout[(size_t)row * N + col] = f2b(v);
                s += v; s2 += v * v;
            }
        s  += __shfl_xor(s, 16);  s  += __shfl_xor(s, 32);
        s2 += __shfl_xor(s2, 16); s2 += __shfl_xor(s2, 32);
        if (quad == 0) {
            int col = n0 + wc * 64 + ni * 16 + l15;
            atomicAdd(&cs[col], s);
            atomicAdd(&cs2[col], s2);
        }
    }
}

// BN scale/shift packed as bf16 pair: ssb[k] = f2b(scale)<<16 | f2b(shift)
// (bf16 params verified numerically R6/R9/R10/R14: absmax 7.6e-6 vs 2e-5 thr)
__global__ void k_bnprep(const float* __restrict__ sum, const float* __restrict__ sumsq,
                         const float* __restrict__ gamma, const float* __restrict__ beta,
                         unsigned* __restrict__ ssb) {
    int j = blockIdx.x * 256 + threadIdx.x;
    float mu = sum[j] * (1.f / B_ROWS);
    float var = sumsq[j] * (1.f / B_ROWS) - mu * mu;
    float sc = gamma[j] * rsqrtf(var + 1e-5f);
    float sh = beta[j] - mu * sc;
    ssb[j] = ((unsigned)f2b(sc) << 16) | (unsigned)f2b(sh);
}

__device__ __forceinline__ short8 bnrelu8(uint4 hv, uint4 sa, uint4 sb) {
    const unsigned short* hu = (const unsigned short*)&hv;
    const unsigned* wa = (const unsigned*)&sa;
    const unsigned* wb = (const unsigned*)&sb;
    short8 o;
#pragma unroll
    for (int j = 0; j < 8; ++j) {
        unsigned w = j < 4 ? wa[j] : wb[j - 4];
        float sc = __uint_as_float(w & 0xffff0000u);
        float sh = __uint_as_float(w << 16);
        float v = fmaxf(b2f(hu[j]) * sc + sh, 0.f);
        o[j] = (short)f2b(v);
    }
    return o;
}

// ---------------------------------------------------------------------------
// GEMM2 (R10's winning version, verbatim): register-staged DOUBLE-BUFFERED,
// lgkm-only barriers. q[M,N] += relu(bn(h))[M,K] * W2T[N,K]^T.
// BM=64, BN=128, BK=32, split-K x4.
__global__ __launch_bounds__(256) void k_gemm2d(
    const unsigned short* __restrict__ A, const unsigned short* __restrict__ Bt,
    float* __restrict__ Cout, const float* __restrict__ bias,
    const unsigned* __restrict__ ssb,
    int M, int N, int K) {
    constexpr int BK = 32, BM = 64, BN = 128;
    constexpr int MI = 2, NI = 4;
    __shared__ __align__(16) short As[2][BM * BK];   // 2 x 4 KB
    __shared__ __align__(16) short Bs[2][BN * BK];   // 2 x 8 KB

    const int t = threadIdx.x;
    const int lane = t & 63, wv = t >> 6;
    const int wr = wv >> 1, wc = wv & 1;
    const int l15 = lane & 15, quad = lane >> 4;
    const int m0 = blockIdx.y * BM, n0 = blockIdx.x * BN;

    const int Kc = K / gridDim.z;
    const int kbeg = blockIdx.z * Kc;
    const int ITERS = Kc / BK;

    const int arow = t >> 2, akc = t & 3;
    const unsigned short* hp = A + (size_t)(m0 + arow) * K + akc * 8;
    const unsigned* ssp = ssb + akc * 8;
    const int awoff = arow * BK + (swz(arow, akc) << 3);

    const unsigned short* bp0 = Bt + (size_t)(n0 + arow) * K + akc * 8;
    const unsigned short* bp1 = Bt + (size_t)(n0 + 64 + arow) * K + akc * 8;
    const int bwoff0 = arow * BK + (swz(arow, akc) << 3);
    const int bwoff1 = (64 + arow) * BK + (swz(64 + arow, akc) << 3);

    f32x4 acc[MI][NI] = {};

    uint4 hreg = *(const uint4*)(hp + kbeg);
    uint4 sa = *(const uint4*)(ssp + kbeg);
    uint4 sb = *(const uint4*)(ssp + kbeg + 4);
    uint4 b0 = *(const uint4*)(bp0 + kbeg);
    uint4 b1 = *(const uint4*)(bp1 + kbeg);

    for (int i = 0; i < ITERS; ++i) {
        const int k0 = kbeg + i * BK;
        short* Ab = As[i & 1];
        short* Bb = Bs[i & 1];

        *(short8*)(Ab + awoff) = bnrelu8(hreg, sa, sb);
        *(uint4*)(Bb + bwoff0) = b0;
        *(uint4*)(Bb + bwoff1) = b1;
        __syncthreads();   // lgkm-only drain

        const int kn = (i + 1 < ITERS) ? k0 + BK : kbeg;
        hreg = *(const uint4*)(hp + kn);
        sa = *(const uint4*)(ssp + kn);
        sb = *(const uint4*)(ssp + kn + 4);
        b0 = *(const uint4*)(bp0 + kn);
        b1 = *(const uint4*)(bp1 + kn);

        short8 af[MI], bfr[NI];
#pragma unroll
        for (int mi = 0; mi < MI; ++mi) {
            int row = wr * 32 + mi * 16 + l15;
            af[mi] = *(const short8*)(Ab + row * BK + (swz(row, quad) << 3));
        }
#pragma unroll
        for (int ni = 0; ni < NI; ++ni) {
            int row = wc * 64 + ni * 16 + l15;
            bfr[ni] = *(const short8*)(Bb + row * BK + (swz(row, quad) << 3));
        }
#pragma unroll
        for (int mi = 0; mi < MI; ++mi)
#pragma unroll
            for (int ni = 0; ni < NI; ++ni)
                acc[mi][ni] = __builtin_amdgcn_mfma_f32_16x16x32_bf16(
                    af[mi], bfr[ni], acc[mi][ni], 0, 0, 0);
    }

#pragma unroll
    for (int mi = 0; mi < MI; ++mi)
#pragma unroll
        for (int ni = 0; ni < NI; ++ni)
#pragma unroll
            for (int r = 0; r < 4; ++r) {
                int row = m0 + wr * 32 + mi * 16 + quad * 4 + r;
                int col = n0 + wc * 64 + ni * 16 + l15;
                float v = acc[mi][ni][r];
                if (blockIdx.z == 0) v += bias[col];
                atomicAdd(&Cout[(size_t)row * N + col], v);
            }
}

// ---------------------------------------------------------------------------
// Fused norm + transpose + cast (R14-proven): per 32-row slab of X [8192,256]
// f32: load to LDS, row inv-norms, write XT [256,8192] bf16 normalized.
// grid (B/32, 4), block 256.
__global__ __launch_bounds__(256) void k_ntc(
    const float* __restrict__ x0, const float* __restrict__ x1,
    const float* __restrict__ x2, const float* __restrict__ x3,
    unsigned short* __restrict__ o0, unsigned short* __restrict__ o1,
    unsigned short* __restrict__ o2, unsigned short* __restrict__ o3) {
    const int z = blockIdx.y;
    const float* x = z == 0 ? x0 : z == 1 ? x1 : z == 2 ? x2 : x3;
    unsigned short* out = z == 0 ? o0 : z == 1 ? o1 : z == 2 ? o2 : o3;

    __shared__ float tile[32][264];
    __shared__ float red[32][8];
    __shared__ float invs[32];
    const int t = threadIdx.x;
    const int r0 = blockIdx.x * 32;

#pragma unroll
    for (int i = 0; i < 8; ++i) {
        int u = i * 256 + t;
        int row = u >> 6, cp = (u & 63) * 4;
        float4 v = *(const float4*)(x + (size_t)(r0 + row) * E_DIM + cp);
        *(float4*)&tile[row][cp] = v;
    }
    __syncthreads();
    {
        int row = t >> 3, cg = (t & 7) * 32;
        float s = 0.f;
#pragma unroll
        for (int j = 0; j < 32; ++j) { float v = tile[row][cg + j]; s += v * v; }
        red[row][t & 7] = s;
    }
    __syncthreads();
    if (t < 32) {
        float s = 0.f;
#pragma unroll
        for (int j = 0; j < 8; ++j) s += red[t][j];
        invs[t] = 1.f / fmaxf(sqrtf(s), 1e-12f);
    }
    __syncthreads();
    {
        int row = t & 31, cb = (t >> 5) * 32;
        float inv = invs[row];
#pragma unroll
        for (int j = 0; j < 32; ++j) {
            int c = cb + j;
            out[(size_t)c * B_ROWS + r0 + row] = f2b(tile[row][c] * inv);
        }
    }
}

// ---------------------------------------------------------------------------
// Gram via MFMA: Mout[a,b] += sum_k AT[a,k]*BT[b,k], AT/BT bf16 [256,8192].
// BM=BN=64, BK=32, swizzled staging, split-K x16; grid (4,4,32).
#define GKS 16
__global__ __launch_bounds__(256) void k_gram(
    const unsigned short* __restrict__ p1T, const unsigned short* __restrict__ q2T,
    const unsigned short* __restrict__ p2T, const unsigned short* __restrict__ q1T,
    float* __restrict__ Ma, float* __restrict__ Mb) {
    constexpr int BK = 32;
    const int mec = blockIdx.z >> 4, kz = blockIdx.z & 15;
    const unsigned short* A = mec ? p2T : p1T;
    const unsigned short* Bt = mec ? q1T : q2T;
    float* Mout = mec ? Mb : Ma;

    __shared__ __align__(16) short As[64 * BK];
    __shared__ __align__(16) short Bs[64 * BK];

    const int t = threadIdx.x;
    const int lane = t & 63, wv = t >> 6;
    const int wr = wv >> 1, wc = wv & 1;
    const int l15 = lane & 15, quad = lane >> 4;
    const int m0 = blockIdx.y * 64, n0 = blockIdx.x * 64;
    const int kbeg = kz * (B_ROWS / GKS);

    f32x4 acc[2][2] = {};

    for (int k0 = kbeg; k0 < kbeg + B_ROWS / GKS; k0 += BK) {
        {
            int row = t >> 2, kc = swz(row, t & 3);
            const short* gpa = (const short*)A + (size_t)(m0 + row) * B_ROWS + k0 + kc * 8;
            short* lpa = As + (size_t)(wv << 6) * 8;
            __builtin_amdgcn_global_load_lds((gas1_t)gpa, (las3_t)lpa, 16, 0, 0);
            const short* gpb = (const short*)Bt + (size_t)(n0 + row) * B_ROWS + k0 + kc * 8;
            short* lpb = Bs + (size_t)(wv << 6) * 8;
            __builtin_amdgcn_global_load_lds((gas1_t)gpb, (las3_t)lpb, 16, 0, 0);
        }
        __syncthreads();

        short8 af[2], bfr[2];
#pragma unroll
        for (int mi = 0; mi < 2; ++mi) {
            int row = wr * 32 + mi * 16 + l15;
            af[mi] = *(const short8*)(As + row * BK + (swz(row, quad) << 3));
        }
#pragma unroll
        for (int ni = 0; ni < 2; ++ni) {
            int row = wc * 32 + ni * 16 + l15;
            bfr[ni] = *(const short8*)(Bs + row * BK + (swz(row, quad) << 3));
        }
#pragma unroll
        for (int mi = 0; mi < 2; ++mi)
#pragma unroll
            for (int ni = 0; ni < 2; ++ni)
                acc[mi][ni] = __builtin_amdgcn_mfma_f32_16x16x32_bf16(
                    af[mi], bfr[ni], acc[mi][ni], 0, 0, 0);
        __syncthreads();
    }

#pragma unroll
    for (int mi = 0; mi < 2; ++mi)
#pragma unroll
        for (int ni = 0; ni < 2; ++ni)
#pragma unroll
            for (int r = 0; r < 4; ++r) {
                int row = m0 + wr * 32 + mi * 16 + quad * 4 + r;
                int col = n0 + wc * 32 + ni * 16 + l15;
                atomicAdd(&Mout[(size_t)row * E_DIM + col], acc[mi][ni][r]);
            }
}

// M2 = M*M (256x256). grid (16,16,2) block 256.
__global__ void k_m2(const float* __restrict__ Ma, const float* __restrict__ Mb,
                     float* __restrict__ M2a, float* __restrict__ M2b) {
    const float* M = blockIdx.z ? Mb : Ma;
    float* M2 = blockIdx.z ? M2b : M2a;
    int b = blockIdx.x * 16 + (threadIdx.x & 15);
    int a = blockIdx.y * 16 + (threadIdx.x >> 4);
    float s = 0.f;
    for (int k = 0; k < E_DIM; ++k) s += M[a * E_DIM + k] * M[k * E_DIM + b];
    M2[a * E_DIM + b] = s;
}

// ---------------------------------------------------------------------------
// Traces, tiled multi-block: grid (8,8,2), block 256.
__global__ __launch_bounds__(256) void k_traces2(
    const float* __restrict__ Ma, const float* __restrict__ M2a,
    const float* __restrict__ Mb, const float* __restrict__ M2b,
    const float* __restrict__ lam, float* __restrict__ out) {
    const float* M  = blockIdx.z ? Mb  : Ma;
    const float* M2 = blockIdx.z ? M2b : M2a;
    const int i0 = blockIdx.y * 32, j0 = blockIdx.x * 32;
    const int t = threadIdx.x, col = t & 31, row = t >> 5;  // row 0..7

    __shared__ float A[32][33], Bt[32][33], A2[32][33], B2[32][33];
#pragma unroll
    for (int r = 0; r < 4; ++r) {
        int rr = r * 8 + row;
        A [rr][col] = M [(i0 + rr) * E_DIM + j0 + col];
        Bt[rr][col] = M [(j0 + rr) * E_DIM + i0 + col];
        A2[rr][col] = M2[(i0 + rr) * E_DIM + j0 + col];
        B2[rr][col] = M2[(j0 + rr) * E_DIM + i0 + col];
    }
    __syncthreads();

    float lamv = lam[0];
    float il = 1.f / lamv;
    float F = -0.5f * lamv * (1.f / B_ROWS);  // -0.5*lam/B
    float c1 = F * il;
    float c2 = -F * 0.5f * il * il;
    float c3 = F * (1.f / 3.f) * il * il * il;
    float c4 = -F * 0.25f * il * il * il * il;

    float s = 0.f;
#pragma unroll
    for (int r = 0; r < 4; ++r) {
        int rr = r * 8 + row;
        float mij = A[rr][col], mji = Bt[col][rr];
        float m2ij = A2[rr][col], m2ji = B2[col][rr];
        s += c2 * mij * mji + c3 * m2ij * mji + c4 * m2ij * m2ji;
        if (i0 + rr == j0 + col) s += c1 * mij;
    }
#pragma unroll
    for (int o = 32; o; o >>= 1) s += __shfl_down(s, o);
    __shared__ float red[4];
    if ((t & 63) == 0) red[t >> 6] = s;
    __syncthreads();
    if (t == 0) atomicAdd(out, red[0] + red[1] + red[2] + red[3]);
}

// ---------------------------------------------------------------------------
extern "C" void kernel_launch(void* const* d_in, const int* in_sizes, int n_in,
                              void* d_out, int out_size, void* d_ws, size_t ws_size,
                              hipStream_t stream) {
    const float* z1 = (const float*)d_in[0];
    const float* z2 = (const float*)d_in[1];
    const float* p1 = (const float*)d_in[2];
    const float* p2 = (const float*)d_in[3];
    const float* W1 = (const float*)d_in[4];
    const float* gamma = (const float*)d_in[5];
    const float* beta = (const float*)d_in[6];
    const float* W2 = (const float*)d_in[7];
    const float* b2 = (const float*)d_in[8];
    const float* lam = (const float*)d_in[9];
    float* out = (float*)d_out;
    char* ws = (char*)d_ws;

    // workspace layout (~89 MB)
    size_t off = 0;
    auto alloc = [&](size_t bytes) { size_t o = off; off += (bytes + 255) & ~(size_t)255; return o; };
    unsigned short* W1T = (unsigned short*)(ws + alloc((size_t)E_DIM * H_DIM * 2));  // [H,E] bf16
    unsigned short* W2T = (unsigned short*)(ws + alloc((size_t)H_DIM * E_DIM * 2));  // [E,H] bf16
    unsigned short* zb  = (unsigned short*)(ws + alloc((size_t)B_ROWS * E_DIM * 2));
    unsigned short* h   = (unsigned short*)(ws + alloc((size_t)B_ROWS * H_DIM * 2));
    // q1,q2,Ma,Mb contiguous -> single memset
    float* q1 = (float*)(ws + alloc((size_t)B_ROWS * E_DIM * 4));
    float* q2 = (float*)(ws + alloc((size_t)B_ROWS * E_DIM * 4));
    float* Ma  = (float*)(ws + alloc((size_t)E_DIM * E_DIM * 4));
    float* Mb  = (float*)(ws + alloc((size_t)E_DIM * E_DIM * 4));
    float* M2a = (float*)(ws + alloc((size_t)E_DIM * E_DIM * 4));
    float* M2b = (float*)(ws + alloc((size_t)E_DIM * E_DIM * 4));
    // two colsum sets (one per view), contiguous -> single memset
    float* cs0 = (float*)(ws + alloc(H_DIM * 4));
    float* cs0q = (float*)(ws + alloc(H_DIM * 4));
    float* cs1 = (float*)(ws + alloc(H_DIM * 4));
    float* cs1q = (float*)(ws + alloc(H_DIM * 4));
    unsigned* ssb = (unsigned*)(ws + alloc(H_DIM * 4));

    // transposed normalized bf16 views alias into h (free after last GEMM2)
    const size_t TSZ = (size_t)E_DIM * B_ROWS;  // 2M elements each
    unsigned short* p1T = h;
    unsigned short* q2T = h + TSZ;
    unsigned short* p2T = h + 2 * TSZ;
    unsigned short* q1T = h + 3 * TSZ;

    // zero accumulation targets (3 memsets total)
    hipMemsetAsync(out, 0, sizeof(float), stream);
    hipMemsetAsync(q1, 0, ((size_t)2 * B_ROWS * E_DIM + 2 * E_DIM * E_DIM) * 4, stream);
    hipMemsetAsync(cs0, 0, (size_t)4 * H_DIM * 4, stream);

    // weight transposes (k-contiguous operands for MFMA)
    k_transpose_cast<<<dim3(H_DIM / 32, E_DIM / 32), 256, 0, stream>>>(W1, W1T, E_DIM, H_DIM);
    k_transpose_cast<<<dim3(E_DIM / 32, H_DIM / 32), 256, 0, stream>>>(W2, W2T, H_DIM, E_DIM);

    const float* zs[2] = {z1, z2};
    float* qs[2] = {q1, q2};
    float* css[2] = {cs0, cs1};
    float* cssq[2] = {cs0q, cs1q};
    for (int v = 0; v < 2; ++v) {
        k_cast_bf16<<<dim3(B_ROWS * E_DIM / 4 / 256), 256, 0, stream>>>(zs[v], zb, B_ROWS * E_DIM / 4);
        // h = z @ W1, with fused column stats
        k_gemm1<<<dim3(H_DIM / 128, B_ROWS / 128), 256, 0, stream>>>(
            zb, W1T, h, css[v], cssq[v], B_ROWS, H_DIM, E_DIM);
        k_bnprep<<<dim3(H_DIM / 256), 256, 0, stream>>>(css[v], cssq[v], gamma, beta, ssb);
        // q = relu(bn(h)) @ W2 + b2 — R10's dbuf register staging, split-K x4
        k_gemm2d<<<dim3(E_DIM / 128, B_ROWS / 64, 4), 256, 0, stream>>>(
            h, W2T, qs[v], b2, ssb, B_ROWS, E_DIM, H_DIM);
    }

    // fused row-norm + transpose + cast of p1,q2,p2,q1 (into h's space)
    k_ntc<<<dim3(B_ROWS / 32, 4), 256, 0, stream>>>(
        p1, q2, p2, q1, p1T, q2T, p2T, q1T);

    k_gram<<<dim3(4, 4, 2 * GKS), 256, 0, stream>>>(p1T, q2T, p2T, q1T, Ma, Mb);
    k_m2<<<dim3(16, 16, 2), 256, 0, stream>>>(Ma, Mb, M2a, M2b);
    k_traces2<<<dim3(8, 8, 2), 256, 0, stream>>>(Ma, M2a, Mb, M2b, lam, out);
}